// Round 2
// baseline (310.161 us; speedup 1.0000x reference)
//
#include <hip/hip_runtime.h>
#include <stdint.h>
#include <math.h>

// SparseBox3DDecoderLite: B=8, Q=100000, C=10, K=1000
// Pipeline: 12-bit-key histogram radix-select -> candidate collect ->
// rank-count top-1000 -> sigmoid rerank -> rank-count sort -> decode boxes.
// Outputs (float32, concatenated): boxes[8,1000,10], final_scores[8,1000],
// labels[8,1000], raw_scores[8,1000]  => 104000 floats.

#define BATCHES 8
#define NQ 100000
#define NEL 1000000   // Q*C per batch
#define NVEC 250000   // NEL/4
#define TOPK 1000
#define NBINS 4096
#define CAP 2048
#define NBLK 64       // blocks per batch for scan kernels
#define NTHR 512

__device__ __forceinline__ unsigned f2key(float f) {
    unsigned b = __float_as_uint(f);
    return b ^ ((b & 0x80000000u) ? 0xFFFFFFFFu : 0x80000000u);
}
__device__ __forceinline__ float key2f(unsigned k) {
    unsigned b = (k & 0x80000000u) ? (k ^ 0x80000000u) : ~k;
    return __uint_as_float(b);
}

__global__ __launch_bounds__(NTHR) void hist_kernel(const float* __restrict__ cls,
                                                    unsigned* __restrict__ ghist) {
    __shared__ unsigned lh[NBINS];
    const int b = blockIdx.x / NBLK;
    const int blk = blockIdx.x % NBLK;
    for (int i = threadIdx.x; i < NBINS; i += NTHR) lh[i] = 0;
    __syncthreads();
    const float4* src = (const float4*)(cls + (size_t)b * NEL);
    for (int i = blk * NTHR + threadIdx.x; i < NVEC; i += NBLK * NTHR) {
        float4 v = src[i];
        atomicAdd(&lh[f2key(v.x) >> 20], 1u);
        atomicAdd(&lh[f2key(v.y) >> 20], 1u);
        atomicAdd(&lh[f2key(v.z) >> 20], 1u);
        atomicAdd(&lh[f2key(v.w) >> 20], 1u);
    }
    __syncthreads();
    unsigned* gh = ghist + (size_t)b * NBINS;
    for (int i = threadIdx.x; i < NBINS; i += NTHR) {
        unsigned v = lh[i];
        if (v) atomicAdd(&gh[i], v);
    }
}

__global__ __launch_bounds__(256) void thresh_kernel(const unsigned* __restrict__ ghist,
                                                     unsigned* __restrict__ tbin) {
    __shared__ unsigned sh[NBINS];
    __shared__ unsigned coarse[256];
    const int b = blockIdx.x;
    for (int i = threadIdx.x; i < NBINS; i += 256) sh[i] = ghist[(size_t)b * NBINS + i];
    __syncthreads();
    unsigned s = 0;
    const int base = threadIdx.x * 16;
#pragma unroll
    for (int j = 0; j < 16; ++j) s += sh[base + j];
    coarse[threadIdx.x] = s;
    __syncthreads();
    if (threadIdx.x == 0) {
        unsigned acc = 0;
        int tb = 0;
        for (int c = 255; c >= 0; --c) {
            if (acc + coarse[c] >= (unsigned)TOPK) {
                for (int bin = c * 16 + 15; bin >= c * 16; --bin) {
                    acc += sh[bin];
                    if (acc >= (unsigned)TOPK) { tb = bin; break; }
                }
                break;
            }
            acc += coarse[c];
        }
        tbin[b] = (unsigned)tb;
    }
}

__global__ __launch_bounds__(NTHR) void collect_kernel(const float* __restrict__ cls,
                                                       const unsigned* __restrict__ tbin,
                                                       unsigned* __restrict__ cnt,
                                                       unsigned long long* __restrict__ cand) {
    const int b = blockIdx.x / NBLK;
    const int blk = blockIdx.x % NBLK;
    const unsigned tb = tbin[b];
    const float4* src = (const float4*)(cls + (size_t)b * NEL);
    unsigned long long* cb = cand + (size_t)b * CAP;
    for (int i = blk * NTHR + threadIdx.x; i < NVEC; i += NBLK * NTHR) {
        float4 v = src[i];
        float xs[4] = {v.x, v.y, v.z, v.w};
#pragma unroll
        for (int j = 0; j < 4; ++j) {
            unsigned k = f2key(xs[j]);
            if ((k >> 20) >= tb) {
                unsigned pos = atomicAdd(&cnt[b], 1u);
                if (pos < CAP) {
                    unsigned idx = (unsigned)(i * 4 + j);
                    cb[pos] = ((unsigned long long)k << 32) |
                              (unsigned long long)(0xFFFFFFFFu - idx);
                }
            }
        }
    }
}

__global__ __launch_bounds__(1024) void finalize_kernel(const float* __restrict__ box_preds,
                                                        const float* __restrict__ quality,
                                                        const unsigned long long* __restrict__ cand,
                                                        const unsigned* __restrict__ cnt,
                                                        float* __restrict__ out) {
    __shared__ unsigned long long arr[CAP];
    __shared__ unsigned long long top[TOPK];
    __shared__ unsigned long long arr2[TOPK];
    const int b = blockIdx.x;
    const int tid = threadIdx.x;
    int n = (int)cnt[b];
    if (n > CAP) n = CAP;
    for (int i = tid; i < CAP; i += 1024)
        arr[i] = (i < n) ? cand[(size_t)b * CAP + i] : 0ull;
    __syncthreads();

    // rank-count selection of top-1000 (composites unique: idx unique)
    unsigned long long m0 = (tid < n) ? arr[tid] : 0ull;
    unsigned long long m1 = (tid + 1024 < n) ? arr[tid + 1024] : 0ull;
    int r0 = 0, r1 = 0;
#pragma unroll 4
    for (int j = 0; j < n; ++j) {
        unsigned long long v = arr[j];   // LDS broadcast (uniform addr)
        r0 += (v > m0);
        r1 += (v > m1);
    }
    if (tid < n && r0 < TOPK) top[r0] = m0;
    if (tid + 1024 < n && r1 < TOPK) top[r1] = m1;
    __syncthreads();

    // decode selected entry + rerank key
    unsigned q = 0, c = 0;
    float s = 0.f, rr = 0.f;
    if (tid < TOPK) {
        unsigned long long mv = top[tid];
        unsigned key = (unsigned)(mv >> 32);
        unsigned idx = 0xFFFFFFFFu - (unsigned)(mv & 0xFFFFFFFFu);
        q = idx / 10u;
        c = idx - q * 10u;
        float logit = key2f(key);
        s = (float)(1.0 / (1.0 + exp(-(double)logit)));          // correctly-rounded f32 sigmoid
        float ctr = quality[((size_t)b * NQ + q) * 2];
        float cs = (float)(1.0 / (1.0 + exp(-(double)ctr)));
        rr = s * cs;                                             // f32 multiply, matches ref
        arr2[tid] = ((unsigned long long)__float_as_uint(rr) << 32) |
                    (unsigned long long)(0xFFFFFFFFu - idx);     // rr desc, idx asc
    }
    __syncthreads();

    if (tid < TOPK) {
        unsigned long long mine = arr2[tid];
        int r = 0;
#pragma unroll 4
        for (int j = 0; j < TOPK; ++j) r += (arr2[j] > mine);
        const size_t row = (size_t)b * TOPK + (size_t)r;
        out[(size_t)BATCHES * TOPK * 10 + row] = rr;        // final_scores
        out[(size_t)BATCHES * TOPK * 11 + row] = (float)c;  // labels_3d
        out[(size_t)BATCHES * TOPK * 12 + row] = s;         // cls_scores_origin
        const float* bp = box_preds + ((size_t)b * NQ + q) * 10;
        float* ob = out + row * 10;
        ob[0] = bp[0];
        ob[1] = bp[1];
        ob[2] = bp[2];
        ob[3] = expf(bp[3]);
        ob[4] = expf(bp[4]);
        ob[5] = expf(bp[5]);
        ob[6] = atan2f(bp[6], bp[7]);
        ob[7] = bp[8];
        ob[8] = bp[9];
        ob[9] = 0.0f;
    }
}

extern "C" void kernel_launch(void* const* d_in, const int* in_sizes, int n_in,
                              void* d_out, int out_size, void* d_ws, size_t ws_size,
                              hipStream_t stream) {
    (void)in_sizes; (void)n_in; (void)out_size; (void)ws_size;
    const float* cls = (const float*)d_in[0];
    const float* box = (const float*)d_in[1];
    const float* qual = (const float*)d_in[2];
    float* out = (float*)d_out;
    char* ws = (char*)d_ws;
    // ws layout: ghist[8*4096 u32]=131072B | cnt[8 u32]=32B | tbin[8 u32]=32B | cand[8*2048 u64]=131072B
    unsigned* ghist = (unsigned*)ws;
    unsigned* cnt = (unsigned*)(ws + 131072);
    unsigned* tbin = (unsigned*)(ws + 131072 + 32);
    unsigned long long* cand = (unsigned long long*)(ws + 131072 + 64);

    hipMemsetAsync(d_ws, 0, 131072 + 32, stream);  // zero ghist + cnt
    hist_kernel<<<BATCHES * NBLK, NTHR, 0, stream>>>(cls, ghist);
    thresh_kernel<<<BATCHES, 256, 0, stream>>>(ghist, tbin);
    collect_kernel<<<BATCHES * NBLK, NTHR, 0, stream>>>(cls, tbin, cnt, cand);
    finalize_kernel<<<BATCHES, 1024, 0, stream>>>(box, qual, cand, cnt, out);
}

// Round 3
// 198.545 us; speedup vs baseline: 1.5622x; 1.5622x over previous
//
#include <hip/hip_runtime.h>
#include <stdint.h>
#include <math.h>

// SparseBox3DDecoderLite: B=8, Q=100000, C=10, K=1000
// Pipeline: 12-bit-key histogram radix-select -> candidate collect (block-
// aggregated atomics) -> rank-count top-1000 -> sigmoid rerank -> rank-count
// sort -> decode boxes.
// Outputs (float32, concatenated): boxes[8,1000,10], final_scores[8,1000],
// labels[8,1000], raw_scores[8,1000]  => 104000 floats.

#define BATCHES 8
#define NQ 100000
#define NEL 1000000   // Q*C per batch
#define NVEC 250000   // NEL/4
#define TOPK 1000
#define NBINS 4096
#define CAP 2048
#define NBLK 64       // blocks per batch for scan kernels
#define NTHR 512
#define STAGE_CAP 512 // per-block candidate staging (expected ~21/block)

__device__ __forceinline__ unsigned f2key(float f) {
    unsigned b = __float_as_uint(f);
    return b ^ ((b & 0x80000000u) ? 0xFFFFFFFFu : 0x80000000u);
}
__device__ __forceinline__ float key2f(unsigned k) {
    unsigned b = (k & 0x80000000u) ? (k ^ 0x80000000u) : ~k;
    return __uint_as_float(b);
}

__global__ __launch_bounds__(NTHR) void hist_kernel(const float* __restrict__ cls,
                                                    unsigned* __restrict__ ghist) {
    __shared__ unsigned lh[NBINS];
    const int b = blockIdx.x / NBLK;
    const int blk = blockIdx.x % NBLK;
    for (int i = threadIdx.x; i < NBINS; i += NTHR) lh[i] = 0;
    __syncthreads();
    const float4* src = (const float4*)(cls + (size_t)b * NEL);
    for (int i = blk * NTHR + threadIdx.x; i < NVEC; i += NBLK * NTHR) {
        float4 v = src[i];
        atomicAdd(&lh[f2key(v.x) >> 20], 1u);
        atomicAdd(&lh[f2key(v.y) >> 20], 1u);
        atomicAdd(&lh[f2key(v.z) >> 20], 1u);
        atomicAdd(&lh[f2key(v.w) >> 20], 1u);
    }
    __syncthreads();
    unsigned* gh = ghist + (size_t)b * NBINS;
    for (int i = threadIdx.x; i < NBINS; i += NTHR) {
        unsigned v = lh[i];
        if (v) atomicAdd(&gh[i], v);   // distinct addresses -> pipelined fine
    }
}

__global__ __launch_bounds__(256) void thresh_kernel(const unsigned* __restrict__ ghist,
                                                     unsigned* __restrict__ tbin) {
    __shared__ unsigned sh[NBINS];
    __shared__ unsigned coarse[256];
    const int b = blockIdx.x;
    for (int i = threadIdx.x; i < NBINS; i += 256) sh[i] = ghist[(size_t)b * NBINS + i];
    __syncthreads();
    unsigned s = 0;
    const int base = threadIdx.x * 16;
#pragma unroll
    for (int j = 0; j < 16; ++j) s += sh[base + j];
    coarse[threadIdx.x] = s;
    __syncthreads();
    if (threadIdx.x == 0) {
        unsigned acc = 0;
        int tb = 0;
        for (int c = 255; c >= 0; --c) {
            if (acc + coarse[c] >= (unsigned)TOPK) {
                for (int bin = c * 16 + 15; bin >= c * 16; --bin) {
                    acc += sh[bin];
                    if (acc >= (unsigned)TOPK) { tb = bin; break; }
                }
                break;
            }
            acc += coarse[c];
        }
        tbin[b] = (unsigned)tb;
    }
}

// Block-aggregated candidate collection: LDS staging + ONE global
// atomicAdd(cnt[b]) per block. Eliminates the 92ns-per-op same-address
// global atomic chain that cost 124us in round 2.
__global__ __launch_bounds__(NTHR) void collect_kernel(const float* __restrict__ cls,
                                                       const unsigned* __restrict__ tbin,
                                                       unsigned* __restrict__ cnt,
                                                       unsigned long long* __restrict__ cand) {
    __shared__ unsigned long long stage[STAGE_CAP];
    __shared__ unsigned lcnt;
    __shared__ unsigned gbase;
    const int b = blockIdx.x / NBLK;
    const int blk = blockIdx.x % NBLK;
    if (threadIdx.x == 0) lcnt = 0;
    __syncthreads();
    const unsigned tb = tbin[b];
    const float4* src = (const float4*)(cls + (size_t)b * NEL);
    unsigned long long* cb = cand + (size_t)b * CAP;
    for (int i = blk * NTHR + threadIdx.x; i < NVEC; i += NBLK * NTHR) {
        float4 v = src[i];
        float xs[4] = {v.x, v.y, v.z, v.w};
#pragma unroll
        for (int j = 0; j < 4; ++j) {
            unsigned k = f2key(xs[j]);
            if ((k >> 20) >= tb) {
                unsigned idx = (unsigned)(i * 4 + j);
                unsigned long long pack = ((unsigned long long)k << 32) |
                                          (unsigned long long)(0xFFFFFFFFu - idx);
                unsigned p = atomicAdd(&lcnt, 1u);
                if (p < STAGE_CAP) {
                    stage[p] = pack;
                } else {                       // exactness fallback (never on this data)
                    unsigned pos = atomicAdd(&cnt[b], 1u);
                    if (pos < CAP) cb[pos] = pack;
                }
            }
        }
    }
    __syncthreads();
    unsigned n = lcnt < STAGE_CAP ? lcnt : STAGE_CAP;
    if (threadIdx.x == 0) gbase = atomicAdd(&cnt[b], n);
    __syncthreads();
    for (unsigned t = threadIdx.x; t < n; t += NTHR) {
        unsigned pos = gbase + t;
        if (pos < CAP) cb[pos] = stage[t];
    }
}

__global__ __launch_bounds__(1024) void finalize_kernel(const float* __restrict__ box_preds,
                                                        const float* __restrict__ quality,
                                                        const unsigned long long* __restrict__ cand,
                                                        const unsigned* __restrict__ cnt,
                                                        float* __restrict__ out) {
    __shared__ unsigned long long arr[CAP];
    __shared__ unsigned long long top[TOPK];
    __shared__ unsigned long long arr2[TOPK];
    const int b = blockIdx.x;
    const int tid = threadIdx.x;
    int n = (int)cnt[b];
    if (n > CAP) n = CAP;
    for (int i = tid; i < CAP; i += 1024)
        arr[i] = (i < n) ? cand[(size_t)b * CAP + i] : 0ull;
    __syncthreads();

    // rank-count selection of top-1000 (composites unique: idx unique)
    unsigned long long m0 = (tid < n) ? arr[tid] : 0ull;
    unsigned long long m1 = (tid + 1024 < n) ? arr[tid + 1024] : 0ull;
    int r0 = 0, r1 = 0;
#pragma unroll 4
    for (int j = 0; j < n; ++j) {
        unsigned long long v = arr[j];   // LDS broadcast (uniform addr)
        r0 += (v > m0);
        r1 += (v > m1);
    }
    if (tid < n && r0 < TOPK) top[r0] = m0;
    if (tid + 1024 < n && r1 < TOPK) top[r1] = m1;
    __syncthreads();

    // decode selected entry + rerank key
    unsigned q = 0, c = 0;
    float s = 0.f, rr = 0.f;
    if (tid < TOPK) {
        unsigned long long mv = top[tid];
        unsigned key = (unsigned)(mv >> 32);
        unsigned idx = 0xFFFFFFFFu - (unsigned)(mv & 0xFFFFFFFFu);
        q = idx / 10u;
        c = idx - q * 10u;
        float logit = key2f(key);
        s = (float)(1.0 / (1.0 + exp(-(double)logit)));          // correctly-rounded f32 sigmoid
        float ctr = quality[((size_t)b * NQ + q) * 2];
        float cs = (float)(1.0 / (1.0 + exp(-(double)ctr)));
        rr = s * cs;                                             // f32 multiply, matches ref
        arr2[tid] = ((unsigned long long)__float_as_uint(rr) << 32) |
                    (unsigned long long)(0xFFFFFFFFu - idx);     // rr desc, idx asc
    }
    __syncthreads();

    if (tid < TOPK) {
        unsigned long long mine = arr2[tid];
        int r = 0;
#pragma unroll 4
        for (int j = 0; j < TOPK; ++j) r += (arr2[j] > mine);
        const size_t row = (size_t)b * TOPK + (size_t)r;
        out[(size_t)BATCHES * TOPK * 10 + row] = rr;        // final_scores
        out[(size_t)BATCHES * TOPK * 11 + row] = (float)c;  // labels_3d
        out[(size_t)BATCHES * TOPK * 12 + row] = s;         // cls_scores_origin
        const float* bp = box_preds + ((size_t)b * NQ + q) * 10;
        float* ob = out + row * 10;
        ob[0] = bp[0];
        ob[1] = bp[1];
        ob[2] = bp[2];
        ob[3] = expf(bp[3]);
        ob[4] = expf(bp[4]);
        ob[5] = expf(bp[5]);
        ob[6] = atan2f(bp[6], bp[7]);
        ob[7] = bp[8];
        ob[8] = bp[9];
        ob[9] = 0.0f;
    }
}

extern "C" void kernel_launch(void* const* d_in, const int* in_sizes, int n_in,
                              void* d_out, int out_size, void* d_ws, size_t ws_size,
                              hipStream_t stream) {
    (void)in_sizes; (void)n_in; (void)out_size; (void)ws_size;
    const float* cls = (const float*)d_in[0];
    const float* box = (const float*)d_in[1];
    const float* qual = (const float*)d_in[2];
    float* out = (float*)d_out;
    char* ws = (char*)d_ws;
    // ws layout: ghist[8*4096 u32]=131072B | cnt[8 u32]=32B | tbin[8 u32]=32B | cand[8*2048 u64]=131072B
    unsigned* ghist = (unsigned*)ws;
    unsigned* cnt = (unsigned*)(ws + 131072);
    unsigned* tbin = (unsigned*)(ws + 131072 + 32);
    unsigned long long* cand = (unsigned long long*)(ws + 131072 + 64);

    hipMemsetAsync(d_ws, 0, 131072 + 32, stream);  // zero ghist + cnt
    hist_kernel<<<BATCHES * NBLK, NTHR, 0, stream>>>(cls, ghist);
    thresh_kernel<<<BATCHES, 256, 0, stream>>>(ghist, tbin);
    collect_kernel<<<BATCHES * NBLK, NTHR, 0, stream>>>(cls, tbin, cnt, cand);
    finalize_kernel<<<BATCHES, 1024, 0, stream>>>(box, qual, cand, cnt, out);
}

// Round 4
// 147.794 us; speedup vs baseline: 2.0986x; 1.3434x over previous
//
#include <hip/hip_runtime.h>
#include <stdint.h>
#include <math.h>

// SparseBox3DDecoderLite: B=8, Q=100000, C=10, K=1000
// Pipeline: 12-bit-key histogram radix-select -> candidate collect (block-
// aggregated atomics) -> WIDE rank-count select (64 blocks) -> WIDE rerank
// sort + decode (64 blocks).
// Outputs (float32, concatenated): boxes[8,1000,10], final_scores[8,1000],
// labels[8,1000], raw_scores[8,1000]  => 104000 floats.

#define BATCHES 8
#define NQ 100000
#define NEL 1000000   // Q*C per batch
#define NVEC 250000   // NEL/4
#define TOPK 1000
#define NBINS 4096
#define CAP 2048
#define NBLK 64       // blocks per batch for scan kernels
#define NTHR 512
#define STAGE_CAP 512 // per-block candidate staging (expected ~21/block)
#define SELBLK 8      // blocks per batch in select_kernel (8*256 == CAP)
#define SRTBLK 8      // blocks per batch in sortdecode_kernel

__device__ __forceinline__ unsigned f2key(float f) {
    unsigned b = __float_as_uint(f);
    return b ^ ((b & 0x80000000u) ? 0xFFFFFFFFu : 0x80000000u);
}
__device__ __forceinline__ float key2f(unsigned k) {
    unsigned b = (k & 0x80000000u) ? (k ^ 0x80000000u) : ~k;
    return __uint_as_float(b);
}

__global__ __launch_bounds__(NTHR) void hist_kernel(const float* __restrict__ cls,
                                                    unsigned* __restrict__ ghist) {
    __shared__ unsigned lh[NBINS];
    const int b = blockIdx.x / NBLK;
    const int blk = blockIdx.x % NBLK;
    for (int i = threadIdx.x; i < NBINS; i += NTHR) lh[i] = 0;
    __syncthreads();
    const float4* src = (const float4*)(cls + (size_t)b * NEL);
    for (int i = blk * NTHR + threadIdx.x; i < NVEC; i += NBLK * NTHR) {
        float4 v = src[i];
        atomicAdd(&lh[f2key(v.x) >> 20], 1u);
        atomicAdd(&lh[f2key(v.y) >> 20], 1u);
        atomicAdd(&lh[f2key(v.z) >> 20], 1u);
        atomicAdd(&lh[f2key(v.w) >> 20], 1u);
    }
    __syncthreads();
    unsigned* gh = ghist + (size_t)b * NBINS;
    for (int i = threadIdx.x; i < NBINS; i += NTHR) {
        unsigned v = lh[i];
        if (v) atomicAdd(&gh[i], v);   // distinct addresses -> pipelined fine
    }
}

__global__ __launch_bounds__(256) void thresh_kernel(const unsigned* __restrict__ ghist,
                                                     unsigned* __restrict__ tbin) {
    __shared__ unsigned sh[NBINS];
    __shared__ unsigned coarse[256];
    const int b = blockIdx.x;
    for (int i = threadIdx.x; i < NBINS; i += 256) sh[i] = ghist[(size_t)b * NBINS + i];
    __syncthreads();
    unsigned s = 0;
    const int base = threadIdx.x * 16;
#pragma unroll
    for (int j = 0; j < 16; ++j) s += sh[base + j];
    coarse[threadIdx.x] = s;
    __syncthreads();
    if (threadIdx.x == 0) {
        unsigned acc = 0;
        int tb = 0;
        for (int c = 255; c >= 0; --c) {
            if (acc + coarse[c] >= (unsigned)TOPK) {
                for (int bin = c * 16 + 15; bin >= c * 16; --bin) {
                    acc += sh[bin];
                    if (acc >= (unsigned)TOPK) { tb = bin; break; }
                }
                break;
            }
            acc += coarse[c];
        }
        tbin[b] = (unsigned)tb;
    }
}

// Block-aggregated candidate collection: LDS staging + ONE global
// atomicAdd(cnt[b]) per block.
__global__ __launch_bounds__(NTHR) void collect_kernel(const float* __restrict__ cls,
                                                       const unsigned* __restrict__ tbin,
                                                       unsigned* __restrict__ cnt,
                                                       unsigned long long* __restrict__ cand) {
    __shared__ unsigned long long stage[STAGE_CAP];
    __shared__ unsigned lcnt;
    __shared__ unsigned gbase;
    const int b = blockIdx.x / NBLK;
    const int blk = blockIdx.x % NBLK;
    if (threadIdx.x == 0) lcnt = 0;
    __syncthreads();
    const unsigned tb = tbin[b];
    const float4* src = (const float4*)(cls + (size_t)b * NEL);
    unsigned long long* cb = cand + (size_t)b * CAP;
    for (int i = blk * NTHR + threadIdx.x; i < NVEC; i += NBLK * NTHR) {
        float4 v = src[i];
        float xs[4] = {v.x, v.y, v.z, v.w};
#pragma unroll
        for (int j = 0; j < 4; ++j) {
            unsigned k = f2key(xs[j]);
            if ((k >> 20) >= tb) {
                unsigned idx = (unsigned)(i * 4 + j);
                unsigned long long pack = ((unsigned long long)k << 32) |
                                          (unsigned long long)(0xFFFFFFFFu - idx);
                unsigned p = atomicAdd(&lcnt, 1u);
                if (p < STAGE_CAP) {
                    stage[p] = pack;
                } else {                       // exactness fallback (never on this data)
                    unsigned pos = atomicAdd(&cnt[b], 1u);
                    if (pos < CAP) cb[pos] = pack;
                }
            }
        }
    }
    __syncthreads();
    unsigned n = lcnt < STAGE_CAP ? lcnt : STAGE_CAP;
    if (threadIdx.x == 0) gbase = atomicAdd(&cnt[b], n);
    __syncthreads();
    for (unsigned t = threadIdx.x; t < n; t += NTHR) {
        unsigned pos = gbase + t;
        if (pos < CAP) cb[pos] = stage[t];
    }
}

// Wide top-1000 selection: 8 blocks/batch, each block stages ALL candidates in
// LDS and rank-counts a 256-candidate chunk with 16-way unrolled broadcast
// reads (ILP). Ranks form a permutation -> scatter by rank, no conflicts.
__global__ __launch_bounds__(256) void select_kernel(const float* __restrict__ quality,
                                                     const unsigned long long* __restrict__ cand,
                                                     const unsigned* __restrict__ cnt,
                                                     unsigned long long* __restrict__ top_rr,
                                                     float* __restrict__ top_s) {
    __shared__ unsigned long long arr[CAP];
    const int b = blockIdx.x / SELBLK;
    const int bk = blockIdx.x % SELBLK;
    const int tid = threadIdx.x;
    int n = (int)cnt[b];
    if (n > CAP) n = CAP;
    for (int i = tid; i < CAP; i += 256)
        arr[i] = (i < n) ? cand[(size_t)b * CAP + i] : 0ull;
    __syncthreads();

    const int ci = bk * 256 + tid;
    if (bk * 256 >= n) return;        // whole block past candidate count
    if (ci < n) {
        const unsigned long long m = arr[ci];
        int r = 0, j = 0;
        for (; j + 16 <= n; j += 16) {
            unsigned long long v0 = arr[j+0],  v1 = arr[j+1],  v2 = arr[j+2],  v3 = arr[j+3];
            unsigned long long v4 = arr[j+4],  v5 = arr[j+5],  v6 = arr[j+6],  v7 = arr[j+7];
            unsigned long long v8 = arr[j+8],  v9 = arr[j+9],  vA = arr[j+10], vB = arr[j+11];
            unsigned long long vC = arr[j+12], vD = arr[j+13], vE = arr[j+14], vF = arr[j+15];
            r += (v0 > m) + (v1 > m) + (v2 > m) + (v3 > m)
               + (v4 > m) + (v5 > m) + (v6 > m) + (v7 > m)
               + (v8 > m) + (v9 > m) + (vA > m) + (vB > m)
               + (vC > m) + (vD > m) + (vE > m) + (vF > m);
        }
        for (; j < n; ++j) r += (arr[j] > m);

        if (r < TOPK) {
            unsigned key = (unsigned)(m >> 32);
            unsigned idx = 0xFFFFFFFFu - (unsigned)(m & 0xFFFFFFFFu);
            unsigned q = idx / 10u;
            float logit = key2f(key);
            float s = (float)(1.0 / (1.0 + exp(-(double)logit)));   // correctly-rounded f32 sigmoid
            float ctr = quality[((size_t)b * NQ + q) * 2];
            float cs = (float)(1.0 / (1.0 + exp(-(double)ctr)));
            float rr = s * cs;                                      // f32 multiply, matches ref
            top_rr[(size_t)b * 1024 + r] = ((unsigned long long)__float_as_uint(rr) << 32) |
                                           (unsigned long long)(0xFFFFFFFFu - idx);  // rr desc, idx asc
            top_s[(size_t)b * 1024 + r] = s;
        }
    }
}

// Wide rerank sort + decode: 8 blocks/batch, each block stages the 1000
// rr-composites and rank-counts a 125-entry chunk, then writes outputs.
__global__ __launch_bounds__(128) void sortdecode_kernel(const float* __restrict__ box_preds,
                                                         const unsigned long long* __restrict__ top_rr,
                                                         const float* __restrict__ top_s,
                                                         float* __restrict__ out) {
    __shared__ unsigned long long rr2[TOPK];
    const int b = blockIdx.x / SRTBLK;
    const int bk = blockIdx.x % SRTBLK;
    const int tid = threadIdx.x;
    for (int i = tid; i < TOPK; i += 128)
        rr2[i] = top_rr[(size_t)b * 1024 + i];
    __syncthreads();

    const int p = bk * 125 + tid;     // this thread's selection-rank entry
    if (p < TOPK && tid < 125) {
        const unsigned long long mine = rr2[p];
        int r = 0, j = 0;
        for (; j + 16 <= TOPK; j += 16) {
            unsigned long long v0 = rr2[j+0],  v1 = rr2[j+1],  v2 = rr2[j+2],  v3 = rr2[j+3];
            unsigned long long v4 = rr2[j+4],  v5 = rr2[j+5],  v6 = rr2[j+6],  v7 = rr2[j+7];
            unsigned long long v8 = rr2[j+8],  v9 = rr2[j+9],  vA = rr2[j+10], vB = rr2[j+11];
            unsigned long long vC = rr2[j+12], vD = rr2[j+13], vE = rr2[j+14], vF = rr2[j+15];
            r += (v0 > mine) + (v1 > mine) + (v2 > mine) + (v3 > mine)
               + (v4 > mine) + (v5 > mine) + (v6 > mine) + (v7 > mine)
               + (v8 > mine) + (v9 > mine) + (vA > mine) + (vB > mine)
               + (vC > mine) + (vD > mine) + (vE > mine) + (vF > mine);
        }
        for (; j < TOPK; ++j) r += (rr2[j] > mine);

        unsigned idx = 0xFFFFFFFFu - (unsigned)(mine & 0xFFFFFFFFu);
        float rr = __uint_as_float((unsigned)(mine >> 32));   // rr > 0: raw bits
        unsigned q = idx / 10u;
        unsigned c = idx - q * 10u;
        float s = top_s[(size_t)b * 1024 + p];

        const size_t row = (size_t)b * TOPK + (size_t)r;
        out[(size_t)BATCHES * TOPK * 10 + row] = rr;        // final_scores
        out[(size_t)BATCHES * TOPK * 11 + row] = (float)c;  // labels_3d
        out[(size_t)BATCHES * TOPK * 12 + row] = s;         // cls_scores_origin
        const float* bp = box_preds + ((size_t)b * NQ + q) * 10;
        float* ob = out + row * 10;
        ob[0] = bp[0];
        ob[1] = bp[1];
        ob[2] = bp[2];
        ob[3] = expf(bp[3]);
        ob[4] = expf(bp[4]);
        ob[5] = expf(bp[5]);
        ob[6] = atan2f(bp[6], bp[7]);
        ob[7] = bp[8];
        ob[8] = bp[9];
        ob[9] = 0.0f;
    }
}

extern "C" void kernel_launch(void* const* d_in, const int* in_sizes, int n_in,
                              void* d_out, int out_size, void* d_ws, size_t ws_size,
                              hipStream_t stream) {
    (void)in_sizes; (void)n_in; (void)out_size; (void)ws_size;
    const float* cls = (const float*)d_in[0];
    const float* box = (const float*)d_in[1];
    const float* qual = (const float*)d_in[2];
    float* out = (float*)d_out;
    char* ws = (char*)d_ws;
    // ws layout: ghist[8*4096 u32]=131072B | cnt[8 u32]=32B | tbin[8 u32]=32B |
    //            cand[8*2048 u64]=131072B | top_rr[8*1024 u64]=65536B | top_s[8*1024 f32]=32768B
    unsigned* ghist = (unsigned*)ws;
    unsigned* cnt = (unsigned*)(ws + 131072);
    unsigned* tbin = (unsigned*)(ws + 131072 + 32);
    unsigned long long* cand = (unsigned long long*)(ws + 131072 + 64);
    unsigned long long* top_rr = (unsigned long long*)(ws + 131072 + 64 + 131072);
    float* top_s = (float*)(ws + 131072 + 64 + 131072 + 65536);

    hipMemsetAsync(d_ws, 0, 131072 + 32, stream);  // zero ghist + cnt
    hist_kernel<<<BATCHES * NBLK, NTHR, 0, stream>>>(cls, ghist);
    thresh_kernel<<<BATCHES, 256, 0, stream>>>(ghist, tbin);
    collect_kernel<<<BATCHES * NBLK, NTHR, 0, stream>>>(cls, tbin, cnt, cand);
    select_kernel<<<BATCHES * SELBLK, 256, 0, stream>>>(qual, cand, cnt, top_rr, top_s);
    sortdecode_kernel<<<BATCHES * SRTBLK, 128, 0, stream>>>(box, top_rr, top_s, out);
}